// Round 7
// baseline (471.956 us; speedup 1.0000x reference)
//
#include <hip/hip_runtime.h>

// Problem constants
constexpr int Bb = 1024;   // batch
constexpr int Ii = 256;    // in features
constexpr int Oo = 256;    // out features
constexpr int Kk = 128;    // knots
constexpr int NBLK = 1024; // fused grid (4 blocks/CU guaranteed -> co-resident)

typedef unsigned short u16;
typedef unsigned int u32;
typedef u16 ushort4v __attribute__((ext_vector_type(4)));

__device__ __forceinline__ float bf16u_to_f(u16 u) {
    union { u32 ui; float f; } c; c.ui = ((u32)u) << 16; return c.f;
}
__device__ __forceinline__ u16 f_to_bf16(float f) {  // round-to-nearest-even
    union { float f; u32 u; } c; c.f = f;
    u32 r = c.u + 0x7fffu + ((c.u >> 16) & 1u);
    return (u16)(r >> 16);
}

// Two-level device-wide barrier. bar[which*16 + g] = per-group arrival
// counters (8 groups of 128 blocks, g = blk&7), bar[which*16+15] = master.
// Release: __threadfence (agent) before arrival; acquire: fence after spin.
// Bounded spin -> a logic error gives wrong answer, not a hang.
__device__ __forceinline__ void gbar(u32* bar, int which) {
    __syncthreads();
    if (threadIdx.x == 0) {
        __threadfence();
        u32 g = blockIdx.x & 7;
        u32 old = __hip_atomic_fetch_add(&bar[which * 16 + g], 1u,
                                         __ATOMIC_ACQ_REL, __HIP_MEMORY_SCOPE_AGENT);
        if (old == (NBLK / 8 - 1))
            __hip_atomic_fetch_add(&bar[which * 16 + 15], 1u,
                                   __ATOMIC_ACQ_REL, __HIP_MEMORY_SCOPE_AGENT);
        for (int spin = 0; spin < (1 << 24); ++spin) {
            if (__hip_atomic_load(&bar[which * 16 + 15], __ATOMIC_ACQUIRE,
                                  __HIP_MEMORY_SCOPE_AGENT) >= 8u) break;
            __builtin_amdgcn_s_sleep(4);
        }
        __threadfence();
    }
    __syncthreads();
}

// One fused kernel: A (prep + coeff transpose) | barrier | B (gather-accum)
// | barrier | C (chunk reduce + bias). 1024 blocks x 256 threads.
__global__ __launch_bounds__(256, 4) void kfused(
        const float* __restrict__ x, const float* __restrict__ wbase,
        const float* __restrict__ cs, const float* __restrict__ scale,
        const float* __restrict__ bias, float* __restrict__ out,
        float4* fls, u16* cp, float* wt, float4* part4, u32* bar) {
    __shared__ u16 T[64 * 136];      // 17.0 KB transpose tile [k_local][o_local]
    __shared__ float4 sf[256];       // 4 KB: [il][bl] 32 i x 8 b

    const int t = threadIdx.x;
    const int blk = blockIdx.x;
    const int gid = blk * 256 + t;

    // ---------- Phase A1: per-(b,i) prep table, [b][i] layout ----------
    {
        float xv = x[gid];                       // gid = b*Ii + i, coalesced
        float e2 = __expf(2.f * xv);
        float p = 1.f - 2.f / (e2 + 1.f);        // tanh
        float s = p / (1.f + __expf(-p));        // silu(p)
        float c = fminf(fmaxf(p, -1.f), 1.f);
        float scaled = (c + 1.f) * ((float)(Kk - 1) * 0.5f);
        int l = (int)floorf(scaled);
        l = min(max(l, 0), Kk - 1);
        int rr = min(l + 1, Kk - 1);
        float f = scaled - (float)l;
        float4 v;
        v.x = f;
        v.y = s;
        v.z = __int_as_float(l * (Oo * 2));      // byte ofs into bf16 [k][o] slab
        v.w = __int_as_float(rr * (Oo * 2));
        fls[gid] = v;
        if (gid < Ii * Oo)                       // Wt[i][o] = W[o][i]
            wt[gid] = wbase[(gid & 255) * Ii + (gid >> 8)];
    }

    // ---------- Phase A2: transpose+scale Cs[o][i][k] -> Cp[i][k][o] bf16 ----
    // 1024 tiles: (i, o-half, k-half), tile = 128 o x 64 k. chunk = blk&7 so
    // chunk c's Cp slice is written by XCD c (matches phase-B readers).
    {
        int c = blk & 7, u = blk >> 3;           // u in 0..127
        int i = c * 32 + (u & 31);
        int oh = (u >> 5) & 1, kh = u >> 6;      // o-half, k-half
        int o0 = oh * 128, kb = kh * 64;
        const float4* cs4 = (const float4*)cs;
        int q = t & 3, r0 = t >> 2;              // 4 threads/row, r0 0..63
#pragma unroll
        for (int h = 0; h < 2; ++h) {
            int r = r0 + h * 64;                 // o_local 0..127
            int o = o0 + r;
            float sc = scale[o * Ii + i];
            const float4* src = cs4 + (size_t)(o * Ii + i) * (Kk / 4) + kh * 16 + q * 4;
#pragma unroll
            for (int j = 0; j < 4; ++j) {
                float4 val = src[j];
                int kk = (q * 4 + j) * 4;        // k_local 0..63 (step 4)
                T[(kk + 0) * 136 + r] = f_to_bf16(val.x * sc);
                T[(kk + 1) * 136 + r] = f_to_bf16(val.y * sc);
                T[(kk + 2) * 136 + r] = f_to_bf16(val.z * sc);
                T[(kk + 3) * 136 + r] = f_to_bf16(val.w * sc);
            }
        }
        __syncthreads();
        int og = t & 31, kg = t >> 5;            // 4 consecutive o; 8 k's each
#pragma unroll
        for (int m = 0; m < 8; ++m) {
            int kl = kg * 8 + m;
            ushort4v v4;
            v4.x = T[kl * 136 + og * 4 + 0];
            v4.y = T[kl * 136 + og * 4 + 1];
            v4.z = T[kl * 136 + og * 4 + 2];
            v4.w = T[kl * 136 + og * 4 + 3];
            *(ushort4v*)&cp[((size_t)i * Kk + kb + kl) * Oo + o0 + og * 4] = v4;
        }
    }

    gbar(bar, 0);

    // ---------- Phase B: gather-accumulate ----------
    // block = (b-tile of 8, chunk of 32 i); chunk = blk&7 -> reads the Cp
    // slice its own XCD just wrote (L2-warm). Thread: 4 o x 2 b.
    {
        int c = blk & 7, u = blk >> 3;
        int b0 = u * 8, i0 = c * 32;
        { int il = t >> 3, bl = t & 7;
          sf[t] = fls[(size_t)(b0 + bl) * Ii + i0 + il]; }
        __syncthreads();

        int oq = t & 63, bh = t >> 6;            // o-quad; b = b0+bh, b0+bh+4
        float a00=0.f,a01=0.f,a02=0.f,a03=0.f;
        float a10=0.f,a11=0.f,a12=0.f,a13=0.f;
        const char* cbase = (const char*)cp + (size_t)i0 * (Kk * Oo * 2) + oq * 8;
        const float4* wt4 = (const float4*)wt;
#pragma unroll 2
        for (int il = 0; il < 32; ++il) {
            const char* ci = cbase + (size_t)il * (Kk * Oo * 2);
            float4 w = wt4[(i0 + il) * (Oo / 4) + oq];
            float4 v0 = sf[il * 8 + bh];
            float4 v1 = sf[il * 8 + bh + 4];
            ushort4v cl0 = *(const ushort4v*)(ci + __float_as_int(v0.z));
            ushort4v cr0 = *(const ushort4v*)(ci + __float_as_int(v0.w));
            ushort4v cl1 = *(const ushort4v*)(ci + __float_as_int(v1.z));
            ushort4v cr1 = *(const ushort4v*)(ci + __float_as_int(v1.w));
            float f0 = v0.x, g0 = 1.f - v0.x, s0 = v0.y;
            float f1 = v1.x, g1 = 1.f - v1.x, s1 = v1.y;
            a00 = fmaf(s0, w.x, a00); a01 = fmaf(s0, w.y, a01);
            a02 = fmaf(s0, w.z, a02); a03 = fmaf(s0, w.w, a03);
            a10 = fmaf(s1, w.x, a10); a11 = fmaf(s1, w.y, a11);
            a12 = fmaf(s1, w.z, a12); a13 = fmaf(s1, w.w, a13);
            a00 = fmaf(g0, bf16u_to_f(cl0.x), a00); a00 = fmaf(f0, bf16u_to_f(cr0.x), a00);
            a01 = fmaf(g0, bf16u_to_f(cl0.y), a01); a01 = fmaf(f0, bf16u_to_f(cr0.y), a01);
            a02 = fmaf(g0, bf16u_to_f(cl0.z), a02); a02 = fmaf(f0, bf16u_to_f(cr0.z), a02);
            a03 = fmaf(g0, bf16u_to_f(cl0.w), a03); a03 = fmaf(f0, bf16u_to_f(cr0.w), a03);
            a10 = fmaf(g1, bf16u_to_f(cl1.x), a10); a10 = fmaf(f1, bf16u_to_f(cr1.x), a10);
            a11 = fmaf(g1, bf16u_to_f(cl1.y), a11); a11 = fmaf(f1, bf16u_to_f(cr1.y), a11);
            a12 = fmaf(g1, bf16u_to_f(cl1.z), a12); a12 = fmaf(f1, bf16u_to_f(cr1.z), a12);
            a13 = fmaf(g1, bf16u_to_f(cl1.w), a13); a13 = fmaf(f1, bf16u_to_f(cr1.w), a13);
        }
        size_t cstride = (size_t)(Bb * Oo / 4);
        float4 r0; r0.x=a00; r0.y=a01; r0.z=a02; r0.w=a03;
        float4 r1; r1.x=a10; r1.y=a11; r1.z=a12; r1.w=a13;
        part4[c * cstride + (size_t)(b0 + bh) * (Oo / 4) + oq] = r0;
        part4[c * cstride + (size_t)(b0 + bh + 4) * (Oo / 4) + oq] = r1;
    }

    gbar(bar, 1);

    // ---------- Phase C: reduce 8 chunks + bias ----------
    {
        float sum = bias[gid & (Oo - 1)];
        const float* p = (const float*)part4;
#pragma unroll
        for (int cc = 0; cc < 8; ++cc)
            sum += p[(size_t)cc * (Bb * Oo) + gid];
        out[gid] = sum;                          // gid = b*Oo + o
    }
}

extern "C" void kernel_launch(void* const* d_in, const int* in_sizes, int n_in,
                              void* d_out, int out_size, void* d_ws, size_t ws_size,
                              hipStream_t stream) {
    const float* x     = (const float*)d_in[0];
    const float* wbase = (const float*)d_in[1];
    const float* coeff = (const float*)d_in[2];
    const float* scale = (const float*)d_in[3];
    const float* bias  = (const float*)d_in[4];
    float* out = (float*)d_out;

    char* ws = (char*)d_ws;
    float4* fls   = (float4*)ws;                          // 4 MB @ 0
    u16*    cp    = (u16*)(ws + (4u << 20));              // 16 MB @ 4M
    float*  wt    = (float*)(ws + (20u << 20));           // 256 KB @ 20M
    float4* part4 = (float4*)(ws + (21u << 20));          // 8 MB @ 21M
    u32*    bar   = (u32*)(ws + (64u << 20));             // barrier state @ 64M

    hipMemsetAsync(bar, 0, 256, stream);                  // zero barrier counters
    kfused<<<NBLK, 256, 0, stream>>>(x, wbase, coeff, scale, bias, out,
                                     fls, cp, wt, part4, bar);
}

// Round 8
// 115.772 us; speedup vs baseline: 4.0766x; 4.0766x over previous
//
#include <hip/hip_runtime.h>

// Problem constants
constexpr int Bb = 1024;   // batch
constexpr int Ii = 256;    // in features
constexpr int Oo = 256;    // out features
constexpr int Kk = 128;    // knots
constexpr int NCH = 8;     // i-chunks (XCD-aligned)

typedef unsigned short u16;
typedef u16 ushort4v __attribute__((ext_vector_type(4)));

__device__ __forceinline__ float bf16u_to_f(u16 u) {
    union { unsigned int ui; float f; } c;
    c.ui = ((unsigned int)u) << 16;
    return c.f;
}
__device__ __forceinline__ u16 f_to_bf16(float f) {  // round-to-nearest-even
    union { float f; unsigned int u; } c; c.f = f;
    unsigned int r = c.u + 0x7fffu + ((c.u >> 16) & 1u);
    return (u16)(r >> 16);
}

// Kernel A: permute+scale Cs[o][i][k] -> Cp[i][k][o] bf16 via LDS transpose
// (grid 256 i x 2 o-halves; reads coalesced along k, writes coalesced along
// o; LDS pitch 130 u16 => worst 2-way bank aliasing, free on gfx950).
// Tail on blocks < 256: Wt[i][o] = W[o][i].
__global__ __launch_bounds__(256) void kperm(const float* __restrict__ cs,
                                             const float* __restrict__ scale,
                                             const float* __restrict__ wbase,
                                             u16* __restrict__ cp,
                                             float* __restrict__ wt) {
    __shared__ u16 T[128 * 130];   // rows = o_local (128), pitch 130 ushorts
    int i  = blockIdx.x >> 1;
    int o0 = (blockIdx.x & 1) << 7;   // 0 or 128
    int t = threadIdx.x;

    // Phase 1: load Cs rows (float4 along k), scale, bf16 -> LDS
    {
        int c4 = t & 31;        // float4 index along k (k = c4*4)
        int rb = t >> 5;        // 0..7
        const float4* cs4 = (const float4*)cs;
#pragma unroll
        for (int p = 0; p < 16; ++p) {
            int r = p * 8 + rb;                 // o_local
            int o = o0 + r;
            float sc = scale[o * Ii + i];
            float4 val = cs4[(size_t)(o * Ii + i) * (Kk / 4) + c4];
            unsigned int lo = ((unsigned int)f_to_bf16(val.y * sc) << 16) | f_to_bf16(val.x * sc);
            unsigned int hi = ((unsigned int)f_to_bf16(val.w * sc) << 16) | f_to_bf16(val.z * sc);
            *(unsigned int*)&T[r * 130 + c4 * 4]     = lo;
            *(unsigned int*)&T[r * 130 + c4 * 4 + 2] = hi;
        }
    }
    __syncthreads();
    // Phase 2: write Cp[i][k][o0..o0+128], lanes <-> o (coalesced stores)
    {
        int ol = t & 127;
        int kh = t >> 7;        // 0..1
        u16* dst = cp + ((size_t)i * Kk) * Oo + o0 + ol;
#pragma unroll
        for (int p = 0; p < 64; ++p) {
            int k = p * 2 + kh;
            dst[(size_t)k * Oo] = T[ol * 130 + k];
        }
    }
    // Tail: Wt[i][o] = W[o][i] (65536 elems across blocks 0..255)
    if (blockIdx.x < 256) {
        int gid = blockIdx.x * 256 + t;
        wt[gid] = wbase[(gid & 255) * Ii + (gid >> 8)];
    }
}

// Kernel B: main accumulation with in-block prep. 2048 blocks = 256 b-tiles
// (4 b) x 8 i-chunks (32 i). Each (b,i) pair belongs to exactly ONE block ->
// prep (tanh/silu/frac/row-offsets) computed here from x, no fls round-trip.
// chunk = blk & 7 -> XCD-aligned (round-robin dispatch), chunk's Cp slice is
// 2 MB <= 4 MB XCD L2. Thread owns 1 b x 4 o, 32 i iterations.
// Partials to part[chunk][b][o] (plain stores, unique writer); kreduce sums.
__global__ __launch_bounds__(256, 4) void kmain(const float* __restrict__ x,
                                                const char* __restrict__ cpb,
                                                const float4* __restrict__ wt4,
                                                float4* __restrict__ part4) {
    __shared__ float4 sf[128];           // [il][bl] : 32 i x 4 b
    int t = threadIdx.x;
    int blk = blockIdx.x;
    int chunk = blk & (NCH - 1);
    int b0 = (blk >> 3) << 2;            // b-tile * 4
    int i0 = chunk << 5;                 // 32 i per chunk

    if (t < 128) {
        int il = t >> 2, bl = t & 3;     // sf[t] layout == [il][bl]
        float xv = x[(size_t)(b0 + bl) * Ii + i0 + il];
        float e2 = __expf(2.f * xv);
        float p = 1.f - 2.f / (e2 + 1.f);   // tanh
        float s = p / (1.f + __expf(-p));   // silu(p)
        float c = fminf(fmaxf(p, -1.f), 1.f);
        float scaled = (c + 1.f) * ((float)(Kk - 1) * 0.5f);
        int l = (int)floorf(scaled);
        l = min(max(l, 0), Kk - 1);
        int rr = min(l + 1, Kk - 1);
        float4 v;
        v.x = scaled - (float)l;             // frac
        v.y = s;                             // silu
        v.z = __int_as_float(l * (Oo * 2));  // byte ofs, left row in [k][o] slab
        v.w = __int_as_float(rr * (Oo * 2)); // byte ofs, right row
        sf[t] = v;
    }
    __syncthreads();

    int oq = t & 63;                     // o = oq*4 .. oq*4+3
    int bh = t >> 6;                     // 0..3 -> b = b0 + bh

    float a0 = 0.f, a1 = 0.f, a2 = 0.f, a3 = 0.f;
    const char* cbase = cpb + (size_t)i0 * (Kk * Oo * 2) + oq * 8;
#pragma unroll 8
    for (int il = 0; il < 32; ++il) {
        float4 v = sf[il * 4 + bh];                      // LDS broadcast
        float4 w = wt4[(i0 + il) * (Oo / 4) + oq];       // coalesced, L1-hot
        const char* ci = cbase + (size_t)il * (Kk * Oo * 2);
        ushort4v cl = *(const ushort4v*)(ci + __float_as_int(v.z));
        ushort4v cr = *(const ushort4v*)(ci + __float_as_int(v.w));
        float f = v.x, g = 1.f - v.x, s = v.y;
        a0 = fmaf(s, w.x, a0);
        a1 = fmaf(s, w.y, a1);
        a2 = fmaf(s, w.z, a2);
        a3 = fmaf(s, w.w, a3);
        a0 = fmaf(g, bf16u_to_f(cl.x), a0);
        a1 = fmaf(g, bf16u_to_f(cl.y), a1);
        a2 = fmaf(g, bf16u_to_f(cl.z), a2);
        a3 = fmaf(g, bf16u_to_f(cl.w), a3);
        a0 = fmaf(f, bf16u_to_f(cr.x), a0);
        a1 = fmaf(f, bf16u_to_f(cr.y), a1);
        a2 = fmaf(f, bf16u_to_f(cr.z), a2);
        a3 = fmaf(f, bf16u_to_f(cr.w), a3);
    }
    float4 r; r.x = a0; r.y = a1; r.z = a2; r.w = a3;
    part4[(size_t)chunk * (Bb * Oo / 4) + (size_t)(b0 + bh) * (Oo / 4) + oq] = r;
}

// Kernel C: out[b][o] = bias[o] + sum_c partial[c][b][o]. 256 blocks.
__global__ __launch_bounds__(256) void kreduce(const float4* __restrict__ part4,
                                               const float4* __restrict__ bias4,
                                               float4* __restrict__ out4) {
    int gid = blockIdx.x * 256 + threadIdx.x;     // = b*64 + o4
    const float4* p = part4 + gid;
    float4 s = p[0];
#pragma unroll
    for (int c = 1; c < NCH; ++c) {
        float4 v = p[(size_t)c * (Bb * Oo / 4)];
        s.x += v.x; s.y += v.y; s.z += v.z; s.w += v.w;
    }
    float4 bv = bias4[gid & 63];
    s.x += bv.x; s.y += bv.y; s.z += bv.z; s.w += bv.w;
    out4[gid] = s;
}

extern "C" void kernel_launch(void* const* d_in, const int* in_sizes, int n_in,
                              void* d_out, int out_size, void* d_ws, size_t ws_size,
                              hipStream_t stream) {
    const float* x     = (const float*)d_in[0];
    const float* wbase = (const float*)d_in[1];
    const float* coeff = (const float*)d_in[2];
    const float* scale = (const float*)d_in[3];
    const float* bias  = (const float*)d_in[4];
    float* out = (float*)d_out;

    char* ws = (char*)d_ws;
    u16*    cp    = (u16*)ws;                             // 16 MB @ 0
    float*  wt    = (float*)(ws + (16u << 20));           // 256 KB @ 16M
    float4* part4 = (float4*)(ws + (17u << 20));          // 8 MB @ 17M

    kperm<<<Ii * 2, 256, 0, stream>>>(coeff, scale, wbase, cp, wt);
    kmain<<<2048, 256, 0, stream>>>(x, (const char*)cp, (const float4*)wt, part4);
    kreduce<<<(Bb * Oo / 4) / 256, 256, 0, stream>>>(part4, (const float4*)bias, (float4*)out);
}

// Round 9
// 110.986 us; speedup vs baseline: 4.2524x; 1.0431x over previous
//
#include <hip/hip_runtime.h>

// Problem constants
constexpr int Bb = 1024;   // batch
constexpr int Ii = 256;    // in features
constexpr int Oo = 256;    // out features
constexpr int Kk = 128;    // knots
constexpr int NCH = 8;     // i-chunks (XCD-aligned)

typedef unsigned short u16;
typedef unsigned int u32;
typedef u16 ushort4v __attribute__((ext_vector_type(4)));

__device__ __forceinline__ float bf16u_to_f(u16 u) {
    union { u32 ui; float f; } c;
    c.ui = ((u32)u) << 16;
    return c.f;
}
__device__ __forceinline__ u16 f_to_bf16(float f) {  // round-to-nearest-even
    union { float f; u32 u; } c; c.f = f;
    u32 r = c.u + 0x7fffu + ((c.u >> 16) & 1u);
    return (u16)(r >> 16);
}

// Kernel A: permute+scale Cs[o][i][k] -> Cp[i][k][o] bf16 via LDS transpose.
// 1024 blocks = 256 i x 2 o-halves x 2 k-halves (4 blocks/CU for latency
// hiding; R8 ran 512 blocks = 2/CU). Tile = 128 o x 64 k. Reads coalesced
// along k, writes coalesced along o. LDS pitch 66 u16 -> conflict-free.
// Tail on blocks < 256: Wt[i][o] = W[o][i].
__global__ __launch_bounds__(256) void kperm(const float* __restrict__ cs,
                                             const float* __restrict__ scale,
                                             const float* __restrict__ wbase,
                                             u16* __restrict__ cp,
                                             float* __restrict__ wt) {
    __shared__ u16 T[128 * 66];       // [o_local][k_local], pitch 66
    int blk = blockIdx.x;
    int i  = blk >> 2;
    int oh = (blk >> 1) & 1, kh = blk & 1;
    int o0 = oh << 7, kb = kh << 6;
    int t = threadIdx.x;

    // Phase 1: load Cs rows (float4 along k), scale, bf16 -> LDS
    {
        int c4 = t & 15;              // float4 index within the 64-k half
        int rb = t >> 4;              // 0..15
        const float4* cs4 = (const float4*)cs;
#pragma unroll
        for (int p = 0; p < 8; ++p) {
            int r = p * 16 + rb;      // o_local 0..127
            int o = o0 + r;
            float sc = scale[o * Ii + i];
            float4 val = cs4[(size_t)(o * Ii + i) * (Kk / 4) + kh * 16 + c4];
            int kl = c4 * 4;
            T[r * 66 + kl + 0] = f_to_bf16(val.x * sc);
            T[r * 66 + kl + 1] = f_to_bf16(val.y * sc);
            T[r * 66 + kl + 2] = f_to_bf16(val.z * sc);
            T[r * 66 + kl + 3] = f_to_bf16(val.w * sc);
        }
    }
    __syncthreads();
    // Phase 2: write Cp[i][kb+kl][o0..o0+128], lanes <-> o (u32 = 2 o)
    {
        int og = t & 63;              // o-pair index (o = og*2, og*2+1)
        int kg = t >> 6;              // 0..3, 16 k-rows each
#pragma unroll
        for (int m = 0; m < 16; ++m) {
            int kl = kg * 16 + m;
            u32 lo = T[(og * 2) * 66 + kl];
            u32 hi = T[(og * 2 + 1) * 66 + kl];
            *(u32*)&cp[((size_t)i * Kk + kb + kl) * Oo + o0 + og * 2] = lo | (hi << 16);
        }
    }
    // Tail: Wt[i][o] = W[o][i] (65536 elems across blocks 0..255)
    if (blk < 256) {
        int gid = blk * 256 + t;
        wt[gid] = wbase[(gid & 255) * Ii + (gid >> 8)];
    }
}

// Kernel B: main accumulation with in-block prep. 2048 blocks = 256 b-tiles
// (4 b) x 8 i-chunks (32 i). chunk = blk & 7 -> XCD-aligned; chunk's Cp
// slice is 2 MB <= 4 MB XCD L2. Thread owns 1 b x 4 o.
// w-rows staged in LDS per 8-i batch: loaded once per BLOCK (R8 loaded the
// same 1 KB row once per WAVE = 4x duplicate L1-return traffic).
// Partials to part[chunk][b][o] (plain stores, unique writer); kreduce sums.
__global__ __launch_bounds__(256, 8) void kmain(const float* __restrict__ x,
                                                const char* __restrict__ cpb,
                                                const float* __restrict__ wt,
                                                float4* __restrict__ part4) {
    __shared__ float4 sf[128];           // [il][bl] : 32 i x 4 b   (2 KB)
    __shared__ float wbuf[8 * 256];      // 8 i-rows of w            (8 KB)
    int t = threadIdx.x;
    int blk = blockIdx.x;
    int chunk = blk & (NCH - 1);
    int b0 = (blk >> 3) << 2;            // b-tile * 4
    int i0 = chunk << 5;                 // 32 i per chunk

    if (t < 128) {
        int il = t >> 2, bl = t & 3;     // sf[t] layout == [il][bl]
        float xv = x[(size_t)(b0 + bl) * Ii + i0 + il];
        float e2 = __expf(2.f * xv);
        float p = 1.f - 2.f / (e2 + 1.f);   // tanh
        float s = p / (1.f + __expf(-p));   // silu(p)
        float c = fminf(fmaxf(p, -1.f), 1.f);
        float scaled = (c + 1.f) * ((float)(Kk - 1) * 0.5f);
        int l = (int)floorf(scaled);
        l = min(max(l, 0), Kk - 1);
        int rr = min(l + 1, Kk - 1);
        float4 v;
        v.x = scaled - (float)l;             // frac
        v.y = s;                             // silu
        v.z = __int_as_float(l * (Oo * 2));  // byte ofs, left row in [k][o] slab
        v.w = __int_as_float(rr * (Oo * 2)); // byte ofs, right row
        sf[t] = v;
    }

    int oq = t & 63;                     // o = oq*4 .. oq*4+3
    int bh = t >> 6;                     // 0..3 -> b = b0 + bh

    float a0 = 0.f, a1 = 0.f, a2 = 0.f, a3 = 0.f;
    const char* cbase = cpb + (size_t)i0 * (Kk * Oo * 2) + oq * 8;

#pragma unroll
    for (int jb = 0; jb < 4; ++jb) {
        __syncthreads();                 // prev batch's wbuf readers done
                                         // (jb==0: doubles as sf-prep barrier)
        {                                // stage 8 w-rows, once per block
            const float* wsrc = wt + (size_t)(i0 + jb * 8) * Oo;
#pragma unroll
            for (int p = 0; p < 8; ++p)
                wbuf[t + p * 256] = wsrc[t + p * 256];
        }
        __syncthreads();
#pragma unroll
        for (int m = 0; m < 8; ++m) {
            int il = jb * 8 + m;
            float4 v = sf[il * 4 + bh];                  // LDS broadcast
            float4 w = *(const float4*)&wbuf[m * 256 + oq * 4];  // conflict-free b128
            const char* ci = cbase + (size_t)il * (Kk * Oo * 2);
            ushort4v cl = *(const ushort4v*)(ci + __float_as_int(v.z));
            ushort4v cr = *(const ushort4v*)(ci + __float_as_int(v.w));
            float f = v.x, g = 1.f - v.x, s = v.y;
            a0 = fmaf(s, w.x, a0);
            a1 = fmaf(s, w.y, a1);
            a2 = fmaf(s, w.z, a2);
            a3 = fmaf(s, w.w, a3);
            a0 = fmaf(g, bf16u_to_f(cl.x), a0);
            a1 = fmaf(g, bf16u_to_f(cl.y), a1);
            a2 = fmaf(g, bf16u_to_f(cl.z), a2);
            a3 = fmaf(g, bf16u_to_f(cl.w), a3);
            a0 = fmaf(f, bf16u_to_f(cr.x), a0);
            a1 = fmaf(f, bf16u_to_f(cr.y), a1);
            a2 = fmaf(f, bf16u_to_f(cr.z), a2);
            a3 = fmaf(f, bf16u_to_f(cr.w), a3);
        }
    }
    float4 r; r.x = a0; r.y = a1; r.z = a2; r.w = a3;
    part4[(size_t)chunk * (Bb * Oo / 4) + (size_t)(b0 + bh) * (Oo / 4) + oq] = r;
}

// Kernel C: out[b][o] = bias[o] + sum_c partial[c][b][o]. 256 blocks.
__global__ __launch_bounds__(256) void kreduce(const float4* __restrict__ part4,
                                               const float4* __restrict__ bias4,
                                               float4* __restrict__ out4) {
    int gid = blockIdx.x * 256 + threadIdx.x;     // = b*64 + o4
    const float4* p = part4 + gid;
    float4 s = p[0];
#pragma unroll
    for (int c = 1; c < NCH; ++c) {
        float4 v = p[(size_t)c * (Bb * Oo / 4)];
        s.x += v.x; s.y += v.y; s.z += v.z; s.w += v.w;
    }
    float4 bv = bias4[gid & 63];
    s.x += bv.x; s.y += bv.y; s.z += bv.z; s.w += bv.w;
    out4[gid] = s;
}

extern "C" void kernel_launch(void* const* d_in, const int* in_sizes, int n_in,
                              void* d_out, int out_size, void* d_ws, size_t ws_size,
                              hipStream_t stream) {
    const float* x     = (const float*)d_in[0];
    const float* wbase = (const float*)d_in[1];
    const float* coeff = (const float*)d_in[2];
    const float* scale = (const float*)d_in[3];
    const float* bias  = (const float*)d_in[4];
    float* out = (float*)d_out;

    char* ws = (char*)d_ws;
    u16*    cp    = (u16*)ws;                             // 16 MB @ 0
    float*  wt    = (float*)(ws + (16u << 20));           // 256 KB @ 16M
    float4* part4 = (float4*)(ws + (17u << 20));          // 8 MB @ 17M

    kperm<<<1024, 256, 0, stream>>>(coeff, scale, wbase, cp, wt);
    kmain<<<2048, 256, 0, stream>>>(x, (const char*)cp, wt, part4);
    kreduce<<<(Bb * Oo / 4) / 256, 256, 0, stream>>>(part4, (const float4*)bias, (float4*)out);
}

// Round 10
// 109.428 us; speedup vs baseline: 4.3129x; 1.0142x over previous
//
#include <hip/hip_runtime.h>

// Problem constants
constexpr int Bb = 1024;   // batch
constexpr int Ii = 256;    // in features
constexpr int Oo = 256;    // out features
constexpr int Kk = 128;    // knots
constexpr int NCH = 8;     // i-chunks (XCD-aligned)

typedef unsigned short u16;
typedef unsigned int u32;
typedef u16 ushort4v __attribute__((ext_vector_type(4)));

__device__ __forceinline__ float bf16u_to_f(u16 u) {
    union { u32 ui; float f; } c;
    c.ui = ((u32)u) << 16;
    return c.f;
}
__device__ __forceinline__ u16 f_to_bf16(float f) {  // round-to-nearest-even
    union { float f; u32 u; } c; c.f = f;
    u32 r = c.u + 0x7fffu + ((c.u >> 16) & 1u);
    return (u16)(r >> 16);
}

// Kernel A: permute+scale Cs[o][i][k] -> Cp[i][k][o] bf16 via LDS transpose.
// 1024 blocks, XCD-ALIGNED numbering: chunk = blk & 7 (same mapping as
// kmain's readers). Chunk c's 2 MB Cp slice is therefore WRITTEN by XCD c,
// and after end-of-kernel writeback stays valid-clean in XCD c's L2 --
// kmain's chunk-c gathers then hit local L2 (~200 cyc) instead of crossing
// to L3 (~600 cyc). Tile = 128 o x 64 k; reads coalesced along k, writes
// coalesced along o; LDS pitch 66 u16 -> conflict-free.
// Tail on blocks < 256: Wt[i][o] = W[o][i].
__global__ __launch_bounds__(256) void kperm(const float* __restrict__ cs,
                                             const float* __restrict__ scale,
                                             const float* __restrict__ wbase,
                                             u16* __restrict__ cp,
                                             float* __restrict__ wt) {
    __shared__ u16 T[128 * 66];       // [o_local][k_local], pitch 66
    int blk = blockIdx.x;
    int chunk = blk & 7;
    int sub = blk >> 3;               // 0..127
    int i  = chunk * 32 + (sub & 31); // i within this XCD's chunk
    int oh = (sub >> 5) & 1, kh = (sub >> 6) & 1;
    int o0 = oh << 7, kb = kh << 6;
    int t = threadIdx.x;

    // Phase 1: load Cs rows (float4 along k), scale, bf16 -> LDS
    {
        int c4 = t & 15;              // float4 index within the 64-k half
        int rb = t >> 4;              // 0..15
        const float4* cs4 = (const float4*)cs;
#pragma unroll
        for (int p = 0; p < 8; ++p) {
            int r = p * 16 + rb;      // o_local 0..127
            int o = o0 + r;
            float sc = scale[o * Ii + i];
            float4 val = cs4[(size_t)(o * Ii + i) * (Kk / 4) + kh * 16 + c4];
            int kl = c4 * 4;
            T[r * 66 + kl + 0] = f_to_bf16(val.x * sc);
            T[r * 66 + kl + 1] = f_to_bf16(val.y * sc);
            T[r * 66 + kl + 2] = f_to_bf16(val.z * sc);
            T[r * 66 + kl + 3] = f_to_bf16(val.w * sc);
        }
    }
    __syncthreads();
    // Phase 2: write Cp[i][kb+kl][o0..o0+128], lanes <-> o (u32 = 2 o)
    {
        int og = t & 63;              // o-pair index (o = og*2, og*2+1)
        int kg = t >> 6;              // 0..3, 16 k-rows each
#pragma unroll
        for (int m = 0; m < 16; ++m) {
            int kl = kg * 16 + m;
            u32 lo = T[(og * 2) * 66 + kl];
            u32 hi = T[(og * 2 + 1) * 66 + kl];
            *(u32*)&cp[((size_t)i * Kk + kb + kl) * Oo + o0 + og * 2] = lo | (hi << 16);
        }
    }
    // Tail: Wt[i][o] = W[o][i] (65536 elems across blocks 0..255)
    if (blk < 256) {
        int gid = blk * 256 + t;
        wt[gid] = wbase[(gid & 255) * Ii + (gid >> 8)];
    }
}

// Kernel B: main accumulation with in-block prep. 2048 blocks = 256 b-tiles
// (4 b) x 8 i-chunks (32 i). chunk = blk & 7 -> XCD-aligned; chunk's Cp
// slice is 2 MB <= 4 MB XCD L2 and (with the matching kperm numbering) was
// written by this same XCD -> local-L2 gather hits. Thread owns 1 b x 4 o.
// w-rows staged in LDS per 8-i batch (once per block, not per wave).
// Partials to part[chunk][b][o] (plain stores, unique writer); kreduce sums.
__global__ __launch_bounds__(256, 8) void kmain(const float* __restrict__ x,
                                                const char* __restrict__ cpb,
                                                const float* __restrict__ wt,
                                                float4* __restrict__ part4) {
    __shared__ float4 sf[128];           // [il][bl] : 32 i x 4 b   (2 KB)
    __shared__ float wbuf[8 * 256];      // 8 i-rows of w            (8 KB)
    int t = threadIdx.x;
    int blk = blockIdx.x;
    int chunk = blk & (NCH - 1);
    int b0 = (blk >> 3) << 2;            // b-tile * 4
    int i0 = chunk << 5;                 // 32 i per chunk

    if (t < 128) {
        int il = t >> 2, bl = t & 3;     // sf[t] layout == [il][bl]
        float xv = x[(size_t)(b0 + bl) * Ii + i0 + il];
        float e2 = __expf(2.f * xv);
        float p = 1.f - 2.f / (e2 + 1.f);   // tanh
        float s = p / (1.f + __expf(-p));   // silu(p)
        float c = fminf(fmaxf(p, -1.f), 1.f);
        float scaled = (c + 1.f) * ((float)(Kk - 1) * 0.5f);
        int l = (int)floorf(scaled);
        l = min(max(l, 0), Kk - 1);
        int rr = min(l + 1, Kk - 1);
        float4 v;
        v.x = scaled - (float)l;             // frac
        v.y = s;                             // silu
        v.z = __int_as_float(l * (Oo * 2));  // byte ofs, left row in [k][o] slab
        v.w = __int_as_float(rr * (Oo * 2)); // byte ofs, right row
        sf[t] = v;
    }

    int oq = t & 63;                     // o = oq*4 .. oq*4+3
    int bh = t >> 6;                     // 0..3 -> b = b0 + bh

    float a0 = 0.f, a1 = 0.f, a2 = 0.f, a3 = 0.f;
    const char* cbase = cpb + (size_t)i0 * (Kk * Oo * 2) + oq * 8;

#pragma unroll
    for (int jb = 0; jb < 4; ++jb) {
        __syncthreads();                 // prev batch's wbuf readers done
                                         // (jb==0: doubles as sf-prep barrier)
        {                                // stage 8 w-rows, once per block
            const float* wsrc = wt + (size_t)(i0 + jb * 8) * Oo;
#pragma unroll
            for (int p = 0; p < 8; ++p)
                wbuf[t + p * 256] = wsrc[t + p * 256];
        }
        __syncthreads();
#pragma unroll
        for (int m = 0; m < 8; ++m) {
            int il = jb * 8 + m;
            float4 v = sf[il * 4 + bh];                  // LDS broadcast
            float4 w = *(const float4*)&wbuf[m * 256 + oq * 4];  // conflict-free b128
            const char* ci = cbase + (size_t)il * (Kk * Oo * 2);
            ushort4v cl = *(const ushort4v*)(ci + __float_as_int(v.z));
            ushort4v cr = *(const ushort4v*)(ci + __float_as_int(v.w));
            float f = v.x, g = 1.f - v.x, s = v.y;
            a0 = fmaf(s, w.x, a0);
            a1 = fmaf(s, w.y, a1);
            a2 = fmaf(s, w.z, a2);
            a3 = fmaf(s, w.w, a3);
            a0 = fmaf(g, bf16u_to_f(cl.x), a0);
            a1 = fmaf(g, bf16u_to_f(cl.y), a1);
            a2 = fmaf(g, bf16u_to_f(cl.z), a2);
            a3 = fmaf(g, bf16u_to_f(cl.w), a3);
            a0 = fmaf(f, bf16u_to_f(cr.x), a0);
            a1 = fmaf(f, bf16u_to_f(cr.y), a1);
            a2 = fmaf(f, bf16u_to_f(cr.z), a2);
            a3 = fmaf(f, bf16u_to_f(cr.w), a3);
        }
    }
    float4 r; r.x = a0; r.y = a1; r.z = a2; r.w = a3;
    part4[(size_t)chunk * (Bb * Oo / 4) + (size_t)(b0 + bh) * (Oo / 4) + oq] = r;
}

// Kernel C: out[b][o] = bias[o] + sum_c partial[c][b][o]. 256 blocks.
__global__ __launch_bounds__(256) void kreduce(const float4* __restrict__ part4,
                                               const float4* __restrict__ bias4,
                                               float4* __restrict__ out4) {
    int gid = blockIdx.x * 256 + threadIdx.x;     // = b*64 + o4
    const float4* p = part4 + gid;
    float4 s = p[0];
#pragma unroll
    for (int c = 1; c < NCH; ++c) {
        float4 v = p[(size_t)c * (Bb * Oo / 4)];
        s.x += v.x; s.y += v.y; s.z += v.z; s.w += v.w;
    }
    float4 bv = bias4[gid & 63];
    s.x += bv.x; s.y += bv.y; s.z += bv.z; s.w += bv.w;
    out4[gid] = s;
}

extern "C" void kernel_launch(void* const* d_in, const int* in_sizes, int n_in,
                              void* d_out, int out_size, void* d_ws, size_t ws_size,
                              hipStream_t stream) {
    const float* x     = (const float*)d_in[0];
    const float* wbase = (const float*)d_in[1];
    const float* coeff = (const float*)d_in[2];
    const float* scale = (const float*)d_in[3];
    const float* bias  = (const float*)d_in[4];
    float* out = (float*)d_out;

    char* ws = (char*)d_ws;
    u16*    cp    = (u16*)ws;                             // 16 MB @ 0
    float*  wt    = (float*)(ws + (16u << 20));           // 256 KB @ 16M
    float4* part4 = (float4*)(ws + (17u << 20));          // 8 MB @ 17M

    kperm<<<1024, 256, 0, stream>>>(coeff, scale, wbase, cp, wt);
    kmain<<<2048, 256, 0, stream>>>(x, (const char*)cp, wt, part4);
    kreduce<<<(Bb * Oo / 4) / 256, 256, 0, stream>>>(part4, (const float4*)bias, (float4*)out);
}

// Round 11
// 108.723 us; speedup vs baseline: 4.3409x; 1.0065x over previous
//
#include <hip/hip_runtime.h>

// Problem constants
constexpr int Bb = 1024;   // batch
constexpr int Ii = 256;    // in features
constexpr int Oo = 256;    // out features
constexpr int Kk = 128;    // knots
constexpr int NCH = 8;     // i-chunks (XCD-aligned)

typedef unsigned short u16;
typedef unsigned int u32;
typedef u16 ushort4v __attribute__((ext_vector_type(4)));

__device__ __forceinline__ float bf16u_to_f(u16 u) {
    union { u32 ui; float f; } c;
    c.ui = ((u32)u) << 16;
    return c.f;
}
__device__ __forceinline__ u16 f_to_bf16(float f) {  // round-to-nearest-even
    union { float f; u32 u; } c; c.f = f;
    u32 r = c.u + 0x7fffu + ((c.u >> 16) & 1u);
    return (u16)(r >> 16);
}

// Kernel A: permute+scale Cs[o][i][k] -> Cp[i][k][o] bf16 via LDS transpose.
// 1024 blocks, XCD-ALIGNED numbering: chunk = blk & 7 (same mapping as
// kmain's readers) -> chunk c's 2 MB Cp slice is written by XCD c and stays
// valid-clean in XCD c's L2 for kmain's local-L2 gather hits.
// Tile = 128 o x 64 k; reads coalesced along k, writes coalesced along o;
// LDS pitch 66 u16 -> conflict-free. Tail on blocks < 256: Wt[i][o]=W[o][i].
__global__ __launch_bounds__(256) void kperm(const float* __restrict__ cs,
                                             const float* __restrict__ scale,
                                             const float* __restrict__ wbase,
                                             u16* __restrict__ cp,
                                             float* __restrict__ wt) {
    __shared__ u16 T[128 * 66];       // [o_local][k_local], pitch 66
    int blk = blockIdx.x;
    int chunk = blk & 7;
    int sub = blk >> 3;               // 0..127
    int i  = chunk * 32 + (sub & 31); // i within this XCD's chunk
    int oh = (sub >> 5) & 1, kh = (sub >> 6) & 1;
    int o0 = oh << 7, kb = kh << 6;
    int t = threadIdx.x;

    // Phase 1: load Cs rows (float4 along k), scale, bf16 -> LDS
    {
        int c4 = t & 15;              // float4 index within the 64-k half
        int rb = t >> 4;              // 0..15
        const float4* cs4 = (const float4*)cs;
#pragma unroll
        for (int p = 0; p < 8; ++p) {
            int r = p * 16 + rb;      // o_local 0..127
            int o = o0 + r;
            float sc = scale[o * Ii + i];
            float4 val = cs4[(size_t)(o * Ii + i) * (Kk / 4) + kh * 16 + c4];
            int kl = c4 * 4;
            T[r * 66 + kl + 0] = f_to_bf16(val.x * sc);
            T[r * 66 + kl + 1] = f_to_bf16(val.y * sc);
            T[r * 66 + kl + 2] = f_to_bf16(val.z * sc);
            T[r * 66 + kl + 3] = f_to_bf16(val.w * sc);
        }
    }
    __syncthreads();
    // Phase 2: write Cp[i][kb+kl][o0..o0+128], lanes <-> o (u32 = 2 o)
    {
        int og = t & 63;              // o-pair index (o = og*2, og*2+1)
        int kg = t >> 6;              // 0..3, 16 k-rows each
#pragma unroll
        for (int m = 0; m < 16; ++m) {
            int kl = kg * 16 + m;
            u32 lo = T[(og * 2) * 66 + kl];
            u32 hi = T[(og * 2 + 1) * 66 + kl];
            *(u32*)&cp[((size_t)i * Kk + kb + kl) * Oo + o0 + og * 2] = lo | (hi << 16);
        }
    }
    // Tail: Wt[i][o] = W[o][i] (65536 elems across blocks 0..255)
    if (blk < 256) {
        int gid = blk * 256 + t;
        wt[gid] = wbase[(gid & 255) * Ii + (gid >> 8)];
    }
}

// Kernel B: main accumulation, 8-b tiles. 1024 blocks = 128 b-tiles (8 b)
// x 8 i-chunks (32 i); grid exactly co-resident at 4 blocks/CU.
// vs R10 (4-b tiles, 2048 blocks): halves wt re-staging traffic (64->32 MB)
// and doubles per-thread gather ILP (4 independent gathers per i).
// Prep: exactly one (b,i) value per thread (no divergent branch).
// chunk = blk & 7 -> XCD-aligned; Cp slice written by same XCD (kperm).
// Partials to part[chunk][b][o] (plain stores, unique writer); kreduce sums.
__global__ __launch_bounds__(256, 4) void kmain(const float* __restrict__ x,
                                                const char* __restrict__ cpb,
                                                const float* __restrict__ wt,
                                                float4* __restrict__ part4) {
    __shared__ float4 sf[256];           // [il][bl] : 32 i x 8 b   (4 KB)
    __shared__ float wbuf[8 * 256];      // 8 i-rows of w           (8 KB)
    int t = threadIdx.x;
    int blk = blockIdx.x;
    int chunk = blk & (NCH - 1);
    int b0 = (blk >> 3) << 3;            // b-tile * 8
    int i0 = chunk << 5;                 // 32 i per chunk

    {                                    // prep: 1 (b,i) per thread
        int il = t & 31, bl = t >> 5;    // coalesced x reads along il
        float xv = x[(size_t)(b0 + bl) * Ii + i0 + il];
        float e2 = __expf(2.f * xv);
        float p = 1.f - 2.f / (e2 + 1.f);   // tanh
        float s = p / (1.f + __expf(-p));   // silu(p)
        float c = fminf(fmaxf(p, -1.f), 1.f);
        float scaled = (c + 1.f) * ((float)(Kk - 1) * 0.5f);
        int l = (int)floorf(scaled);
        l = min(max(l, 0), Kk - 1);
        int rr = min(l + 1, Kk - 1);
        float4 v;
        v.x = scaled - (float)l;             // frac
        v.y = s;                             // silu
        v.z = __int_as_float(l * (Oo * 2));  // byte ofs, left row in [k][o] slab
        v.w = __int_as_float(rr * (Oo * 2)); // byte ofs, right row
        sf[il * 8 + bl] = v;
    }

    int oq = t & 63;                     // o = oq*4 .. oq*4+3
    int bq = t >> 6;                     // 0..3 -> b = b0 + bq*2 + {0,1}

    float a00=0.f,a01=0.f,a02=0.f,a03=0.f;   // b = b0 + bq*2
    float a10=0.f,a11=0.f,a12=0.f,a13=0.f;   // b = b0 + bq*2 + 1
    const char* cbase = cpb + (size_t)i0 * (Kk * Oo * 2) + oq * 8;

#pragma unroll
    for (int jb = 0; jb < 4; ++jb) {
        __syncthreads();                 // prev batch's wbuf readers done
                                         // (jb==0: doubles as sf-prep barrier)
        {                                // stage 8 w-rows, once per block
            const float* wsrc = wt + (size_t)(i0 + jb * 8) * Oo;
#pragma unroll
            for (int p = 0; p < 8; ++p)
                wbuf[t + p * 256] = wsrc[t + p * 256];
        }
        __syncthreads();
#pragma unroll 4
        for (int m = 0; m < 8; ++m) {
            int il = jb * 8 + m;
            float4 v0 = sf[il * 8 + bq * 2];             // LDS broadcast
            float4 v1 = sf[il * 8 + bq * 2 + 1];
            float4 w = *(const float4*)&wbuf[m * 256 + oq * 4];  // b128, no conflicts
            const char* ci = cbase + (size_t)il * (Kk * Oo * 2);
            ushort4v cl0 = *(const ushort4v*)(ci + __float_as_int(v0.z));
            ushort4v cr0 = *(const ushort4v*)(ci + __float_as_int(v0.w));
            ushort4v cl1 = *(const ushort4v*)(ci + __float_as_int(v1.z));
            ushort4v cr1 = *(const ushort4v*)(ci + __float_as_int(v1.w));
            float f0 = v0.x, g0 = 1.f - v0.x, s0 = v0.y;
            float f1 = v1.x, g1 = 1.f - v1.x, s1 = v1.y;
            a00 = fmaf(s0, w.x, a00); a01 = fmaf(s0, w.y, a01);
            a02 = fmaf(s0, w.z, a02); a03 = fmaf(s0, w.w, a03);
            a10 = fmaf(s1, w.x, a10); a11 = fmaf(s1, w.y, a11);
            a12 = fmaf(s1, w.z, a12); a13 = fmaf(s1, w.w, a13);
            a00 = fmaf(g0, bf16u_to_f(cl0.x), a00); a00 = fmaf(f0, bf16u_to_f(cr0.x), a00);
            a01 = fmaf(g0, bf16u_to_f(cl0.y), a01); a01 = fmaf(f0, bf16u_to_f(cr0.y), a01);
            a02 = fmaf(g0, bf16u_to_f(cl0.z), a02); a02 = fmaf(f0, bf16u_to_f(cr0.z), a02);
            a03 = fmaf(g0, bf16u_to_f(cl0.w), a03); a03 = fmaf(f0, bf16u_to_f(cr0.w), a03);
            a10 = fmaf(g1, bf16u_to_f(cl1.x), a10); a10 = fmaf(f1, bf16u_to_f(cr1.x), a10);
            a11 = fmaf(g1, bf16u_to_f(cl1.y), a11); a11 = fmaf(f1, bf16u_to_f(cr1.y), a11);
            a12 = fmaf(g1, bf16u_to_f(cl1.z), a12); a12 = fmaf(f1, bf16u_to_f(cr1.z), a12);
            a13 = fmaf(g1, bf16u_to_f(cl1.w), a13); a13 = fmaf(f1, bf16u_to_f(cr1.w), a13);
        }
    }
    size_t cstride = (size_t)(Bb * Oo / 4);
    float4 r0; r0.x=a00; r0.y=a01; r0.z=a02; r0.w=a03;
    float4 r1; r1.x=a10; r1.y=a11; r1.z=a12; r1.w=a13;
    part4[chunk * cstride + (size_t)(b0 + bq * 2) * (Oo / 4) + oq] = r0;
    part4[chunk * cstride + (size_t)(b0 + bq * 2 + 1) * (Oo / 4) + oq] = r1;
}

// Kernel C: out[b][o] = bias[o] + sum_c partial[c][b][o]. 256 blocks.
__global__ __launch_bounds__(256) void kreduce(const float4* __restrict__ part4,
                                               const float4* __restrict__ bias4,
                                               float4* __restrict__ out4) {
    int gid = blockIdx.x * 256 + threadIdx.x;     // = b*64 + o4
    const float4* p = part4 + gid;
    float4 s = p[0];
#pragma unroll
    for (int c = 1; c < NCH; ++c) {
        float4 v = p[(size_t)c * (Bb * Oo / 4)];
        s.x += v.x; s.y += v.y; s.z += v.z; s.w += v.w;
    }
    float4 bv = bias4[gid & 63];
    s.x += bv.x; s.y += bv.y; s.z += bv.z; s.w += bv.w;
    out4[gid] = s;
}

extern "C" void kernel_launch(void* const* d_in, const int* in_sizes, int n_in,
                              void* d_out, int out_size, void* d_ws, size_t ws_size,
                              hipStream_t stream) {
    const float* x     = (const float*)d_in[0];
    const float* wbase = (const float*)d_in[1];
    const float* coeff = (const float*)d_in[2];
    const float* scale = (const float*)d_in[3];
    const float* bias  = (const float*)d_in[4];
    float* out = (float*)d_out;

    char* ws = (char*)d_ws;
    u16*    cp    = (u16*)ws;                             // 16 MB @ 0
    float*  wt    = (float*)(ws + (16u << 20));           // 256 KB @ 16M
    float4* part4 = (float4*)(ws + (17u << 20));          // 8 MB @ 17M

    kperm<<<1024, 256, 0, stream>>>(coeff, scale, wbase, cp, wt);
    kmain<<<1024, 256, 0, stream>>>(x, (const char*)cp, wt, part4);
    kreduce<<<(Bb * Oo / 4) / 256, 256, 0, stream>>>(part4, (const float4*)bias, (float4*)out);
}